// Round 2
// baseline (287.563 us; speedup 1.0000x reference)
//
#include <hip/hip_runtime.h>

typedef __attribute__((ext_vector_type(8))) short short8;
typedef __attribute__((ext_vector_type(4))) float float4v;

#define N_PTS 8192
#define DIM   128
#define BM    128

typedef const __attribute__((address_space(1))) void* gptr_t;
typedef __attribute__((address_space(3))) void* lptr_t;

__device__ __forceinline__ unsigned short f2bf(float f) {
    unsigned u = __builtin_bit_cast(unsigned, f);
    u += 0x7fffu + ((u >> 16) & 1u);          // RNE to bf16
    return (unsigned short)(u >> 16);
}
__device__ __forceinline__ float bf2f(unsigned short h) {
    unsigned u = ((unsigned)h) << 16;
    return __builtin_bit_cast(float, u);
}

// ---- pre-pass: fp32 -> bf16 once, XOR-swizzled granules, plus per-row sq ----
// (verbatim from the verified 271 us kernel)
__global__ __launch_bounds__(128)
void prep_kernel(const float* __restrict__ F,
                 unsigned short* __restrict__ bfF,
                 float* __restrict__ sqg) {
    const int row = blockIdx.x * 128 + threadIdx.x;   // 64 blocks x 128 = 8192 rows
    const float* __restrict__ src = F + (size_t)row * DIM;
    unsigned short* dst = bfF + (size_t)row * DIM;
    float s = 0.f;
#pragma unroll
    for (int g = 0; g < 16; ++g) {
        float4v f0 = *(const float4v*)(src + g * 8);
        float4v f1 = *(const float4v*)(src + g * 8 + 4);
        short8 p;
#pragma unroll
        for (int k = 0; k < 4; ++k) {
            unsigned short b0 = f2bf(f0[k]);
            unsigned short b1 = f2bf(f1[k]);
            p[k]     = (short)b0;
            p[k + 4] = (short)b1;
            float v0 = bf2f(b0), v1 = bf2f(b1);
            s += v0 * v0 + v1 * v1;
        }
        *(short8*)(dst + (g ^ (row & 15)) * 8) = p;
    }
    sqg[row] = s;
}

// ---- main: 128x128 output tile per block, bf16 MFMA, DMA staging ----
// Identical to the verified kernel through the k-loop; ONLY the epilogue
// changed: results bounce through Ts (aliasing the dead As+Bs, <=64 KB so
// every LDS address matches the verified kernel's range) and are stored as
// full 512 B row segments via dwordx4 instead of 64 B scalar scatters.
__global__ __launch_bounds__(256, 2)
void fsim_kernel(const unsigned short* __restrict__ bfF,
                 const float* __restrict__ sqg,
                 float* __restrict__ out) {
    __shared__ char smem[65536];
    unsigned short* As = (unsigned short*)smem;            // 32 KB (swizzled bf16)
    unsigned short* Bs = (unsigned short*)(smem + 32768);  // 32 KB
    float*          Ts = (float*)smem;                     // 64 KB, aliases As+Bs
    __shared__ float sqA[BM];
    __shared__ float sqB[BM];

    const int t    = threadIdx.x;
    const int lane = t & 63;
    const int w    = t >> 6;
    const int brow = blockIdx.y;
    const int bcol = blockIdx.x;

    // ---- stage: linear global->LDS DMA, 16 B/lane (unchanged) ----
    const char* gA = (const char*)(bfF + (size_t)brow * BM * DIM);
    const char* gB = (const char*)(bfF + (size_t)bcol * BM * DIM);
    char* lA = (char*)As;
    char* lB = (char*)Bs;
    const int off = w * 8192 + lane * 16;     // each wave copies 8 KB per tile
#pragma unroll
    for (int i = 0; i < 8; ++i) {
        __builtin_amdgcn_global_load_lds((gptr_t)(gA + off + i * 1024),
                                         (lptr_t)(lA + off + i * 1024), 16, 0, 0);
        __builtin_amdgcn_global_load_lds((gptr_t)(gB + off + i * 1024),
                                         (lptr_t)(lB + off + i * 1024), 16, 0, 0);
    }
    if (t < 128) sqA[t] = sqg[brow * BM + t];
    else         sqB[t - 128] = sqg[bcol * BM + (t - 128)];
    __syncthreads();                          // compiler drains vmcnt here

    // ---- MFMA k-loop (unchanged) ----
    const int wr   = (w >> 1) * 64;
    const int wc   = (w & 1) * 64;
    const int lrow = lane & 15;
    const int quad = lane >> 4;

    float4v acc[4][4];
#pragma unroll
    for (int a = 0; a < 4; ++a)
#pragma unroll
        for (int b = 0; b < 4; ++b)
            acc[a][b] = (float4v){0.f, 0.f, 0.f, 0.f};

#pragma unroll
    for (int ks = 0; ks < 4; ++ks) {
        short8 af[4], bfv[4];
        const int g = ks * 4 + quad;          // logical granule along K
#pragma unroll
        for (int mt = 0; mt < 4; ++mt) {
            const int row = wr + mt * 16 + lrow;
            af[mt] = *(const short8*)((const short*)As + row * DIM + ((g ^ (row & 15)) * 8));
        }
#pragma unroll
        for (int nt = 0; nt < 4; ++nt) {
            const int row = wc + nt * 16 + lrow;
            bfv[nt] = *(const short8*)((const short*)Bs + row * DIM + ((g ^ (row & 15)) * 8));
        }
#pragma unroll
        for (int mt = 0; mt < 4; ++mt)
#pragma unroll
            for (int nt = 0; nt < 4; ++nt)
                acc[mt][nt] = __builtin_amdgcn_mfma_f32_16x16x32_bf16(
                    af[mt], bfv[nt], acc[mt][nt], 0, 0, 0);
    }

    __syncthreads();   // all As/Bs LDS reads consumed; Ts may now overwrite

    // ---- bounce: -sqrt(max(0, sq_r + sq_c - 2*gram)) into rotated Ts ----
    // Row m holds its 128 cols as float4-groups rotated by m: group slot
    // pg = (n/4 + m) & 31. Bijective per row; row reads below are conflict-free.
    float scb[4];
#pragma unroll
    for (int nt = 0; nt < 4; ++nt) scb[nt] = sqB[wc + nt * 16 + lrow];
#pragma unroll
    for (int mt = 0; mt < 4; ++mt) {
#pragma unroll
        for (int reg = 0; reg < 4; ++reg) {
            const int m  = wr + mt * 16 + quad * 4 + reg;  // C/D: row=(lane>>4)*4+reg
            const float sr = sqA[m];
#pragma unroll
            for (int nt = 0; nt < 4; ++nt) {
                const int n = wc + nt * 16 + lrow;         // col=lane&15
                float d2 = sr + scb[nt] - 2.0f * acc[mt][nt][reg];
                d2 = d2 > 0.f ? d2 : 0.f;
                const int pg = ((n >> 2) + m) & 31;
                Ts[m * BM + pg * 4 + (n & 3)] = -__builtin_sqrtf(d2);
            }
        }
    }
    __syncthreads();

    // ---- store: 2 rows x 512 B contiguous per dwordx4 instruction ----
    // Wave w owns rows w*32..w*32+31; lanes 0-31 -> even row, 32-63 -> odd row.
    float* obase = out + (size_t)brow * BM * N_PTS + (size_t)bcol * BM;
#pragma unroll
    for (int rr = 0; rr < 16; ++rr) {
        const int m  = w * 32 + rr * 2 + (lane >> 5);
        const int gi = lane & 31;
        const float4v v = *(const float4v*)(Ts + m * BM + ((gi + m) & 31) * 4);
        *(float4v*)(obase + (size_t)m * N_PTS + gi * 4) = v;
    }
}

extern "C" void kernel_launch(void* const* d_in, const int* in_sizes, int n_in,
                              void* d_out, int out_size, void* d_ws, size_t ws_size,
                              hipStream_t stream) {
    const float* F = (const float*)d_in[0];
    float* out = (float*)d_out;
    unsigned short* bfF = (unsigned short*)d_ws;                       // 2 MB bf16
    float* sqg = (float*)((char*)d_ws + (size_t)N_PTS * DIM * 2);      // +32 KB sq

    prep_kernel<<<dim3(N_PTS / 128), 128, 0, stream>>>(F, bfF, sqg);
    dim3 grid(N_PTS / BM, N_PTS / BM);        // 64 x 64
    fsim_kernel<<<grid, 256, 0, stream>>>(bfF, sqg, out);
}